// Round 1
// baseline (1377.710 us; speedup 1.0000x reference)
//
#include <hip/hip_runtime.h>
#include <cstdint>

#define B_    32
#define T_    2048
#define D_    80
#define T2_   511
#define NROW  16352      // B_*T2_
#define GK    720        // INPUT_DIM
#define CBD   512
#define CBS   1024
#define HMASK 8176       // 16352/2
#define HN    2621440    // B_*T_*D_/2

// ---------------- threefry2x32 (exact JAX schedule) ----------------
__host__ __device__ inline uint32_t rotl_(uint32_t v, int d){ return (v<<d)|(v>>(32-d)); }

__host__ __device__ inline void tf2x32(uint32_t k0, uint32_t k1, uint32_t& x0, uint32_t& x1){
  uint32_t ks2 = k0 ^ k1 ^ 0x1BD11BDAu;
  x0 += k0; x1 += k1;
  const int r0[4] = {13,15,26,6}, r1[4] = {17,29,16,24};
#pragma unroll
  for (int i=0;i<4;i++){ x0 += x1; x1 = rotl_(x1, r0[i]); x1 ^= x0; }
  x0 += k1; x1 += ks2 + 1u;
#pragma unroll
  for (int i=0;i<4;i++){ x0 += x1; x1 = rotl_(x1, r1[i]); x1 ^= x0; }
  x0 += ks2; x1 += k0 + 2u;
#pragma unroll
  for (int i=0;i<4;i++){ x0 += x1; x1 = rotl_(x1, r0[i]); x1 ^= x0; }
  x0 += k0; x1 += k1 + 3u;
#pragma unroll
  for (int i=0;i<4;i++){ x0 += x1; x1 = rotl_(x1, r1[i]); x1 ^= x0; }
  x0 += k1; x1 += ks2 + 4u;
#pragma unroll
  for (int i=0;i<4;i++){ x0 += x1; x1 = rotl_(x1, r0[i]); x1 ^= x0; }
  x0 += ks2; x1 += k0 + 5u;
}

// XLA ErfInv32 (Giles) — matches lax.erf_inv f32
__device__ inline float erfinv_f(float x){
  float w = -log1pf(-x*x);
  float p;
  if (w < 5.0f){
    w -= 2.5f;
    p = 2.81022636e-08f;
    p = fmaf(p, w, 3.43273939e-07f);
    p = fmaf(p, w, -3.5233877e-06f);
    p = fmaf(p, w, -4.39150654e-06f);
    p = fmaf(p, w, 0.00021858087f);
    p = fmaf(p, w, -0.00125372503f);
    p = fmaf(p, w, -0.00417768164f);
    p = fmaf(p, w, 0.246640727f);
    p = fmaf(p, w, 1.50140941f);
  } else {
    w = sqrtf(w) - 3.0f;
    p = -0.000200214257f;
    p = fmaf(p, w, 0.000100950558f);
    p = fmaf(p, w, 0.00134934322f);
    p = fmaf(p, w, -0.00367342844f);
    p = fmaf(p, w, 0.00573950773f);
    p = fmaf(p, w, -0.0076224613f);
    p = fmaf(p, w, 0.00943887047f);
    p = fmaf(p, w, 1.00167406f);
    p = fmaf(p, w, 2.83297682f);
  }
  return p * x;
}

__device__ inline int label_len(int L){ return (((L - 3) / 2) - 2) / 2 + 1; }

// ---------------- kernel 1: codebook norms (fp64 acc) ----------------
__global__ void cbnorm_k(const float* __restrict__ cb, float* __restrict__ cbn){
  int c = blockIdx.x, lane = threadIdx.x;
  double s = 0.0;
  for (int k = lane; k < CBD; k += 64){ float v = cb[c*CBD + k]; s += (double)v * (double)v; }
#pragma unroll
  for (int off = 32; off; off >>= 1) s += __shfl_down(s, off);
  if (lane == 0) cbn[c] = (float)s;
}

// ---------------- kernel 2: gather stacked S (coalesced write) ----------------
__global__ void gather_k(const float* __restrict__ raw, float* __restrict__ S){
  int idx = blockIdx.x * 256 + threadIdx.x;   // grid sized exactly NROW*GK
  int n = idx / GK, k = idx - n * GK;
  int b = n / T2_, t2 = n - b * T2_;
  int d = k / 9, rem = k - d * 9;
  int k1 = rem / 3, k2 = rem - 3 * k1;
  int tm = 4 * t2 + 2 * k2 + k1;
  S[idx] = raw[(b * T_ + tm) * D_ + d];
}

// ---------------- kernel 3: GEMM1  T = S(16352x720) * P(720x512) ----------------
__global__ __launch_bounds__(256) void gemm1_k(const float* __restrict__ S, const float* __restrict__ P,
                                               float* __restrict__ Tm){
  __shared__ float sA[16][132];  // [kk][row], padded: stride 132 (16B-aligned, conflict-free)
  __shared__ float sB[16][68];   // [kk][col]
  int n0 = blockIdx.y * 128, c0 = blockIdx.x * 64;
  int tid = threadIdx.x, tx = tid & 15, ty = tid >> 4;
  float acc[8][4] = {};
  for (int k0 = 0; k0 < GK; k0 += 16){
    __syncthreads();
#pragma unroll
    for (int qq = 0; qq < 8; ++qq){
      int q = tid + qq * 256; int r = q >> 4, kk = q & 15;
      int n = n0 + r;
      sA[kk][r] = (n < NROW) ? S[n * GK + k0 + kk] : 0.f;
    }
#pragma unroll
    for (int qq = 0; qq < 4; ++qq){
      int q = tid + qq * 256; int cc = q & 63, kk = q >> 6;
      sB[kk][cc] = P[(k0 + kk) * CBD + c0 + cc];
    }
    __syncthreads();
#pragma unroll
    for (int kk = 0; kk < 16; ++kk){
      float4 a0 = *(const float4*)&sA[kk][ty * 8];
      float4 a1 = *(const float4*)&sA[kk][ty * 8 + 4];
      float4 bv = *(const float4*)&sB[kk][tx * 4];
      float av[8] = {a0.x,a0.y,a0.z,a0.w,a1.x,a1.y,a1.z,a1.w};
      float bw[4] = {bv.x,bv.y,bv.z,bv.w};
#pragma unroll
      for (int i = 0; i < 8; ++i)
#pragma unroll
        for (int j = 0; j < 4; ++j) acc[i][j] = fmaf(av[i], bw[j], acc[i][j]);
    }
  }
#pragma unroll
  for (int i = 0; i < 8; ++i){
    int n = n0 + ty * 8 + i;
    if (n < NROW){
      float4 o; o.x = acc[i][0]; o.y = acc[i][1]; o.z = acc[i][2]; o.w = acc[i][3];
      *(float4*)&Tm[n * CBD + c0 + tx * 4] = o;
    }
  }
}

// ---------------- kernel 4: dist + argmin -> labels ----------------
__global__ __launch_bounds__(256) void dist_k(const float* __restrict__ Tm, const float* __restrict__ cb,
                                              const float* __restrict__ cbn, const int* __restrict__ len,
                                              float* __restrict__ out_lb){
  __shared__ float tl[16][513];
  __shared__ float cl[16][513];
  __shared__ float rv[16][64];
  __shared__ int   ri[16][64];
  int row0 = blockIdx.x * 16;
  int tid = threadIdx.x;
  for (int q = tid; q < 16 * CBD; q += 256){ int r = q >> 9, k = q & 511; tl[r][k] = Tm[(row0 + r) * CBD + k]; }
  int rg = tid & 3, cg = tid >> 2;   // rows rg*4+i ; codes cg + 64*j (j<8), ascending
  float minv[4] = {1e30f, 1e30f, 1e30f, 1e30f};
  int   mini[4] = {0, 0, 0, 0};
  for (int cc0 = 0; cc0 < CBS; cc0 += 512){
    float acc[4][8] = {};
    for (int kt = 0; kt < CBD; kt += 16){
      __syncthreads();
      for (int q = tid; q < 512 * 16; q += 256){
        int c = q >> 4, kk = q & 15;
        cl[kk][c] = cb[(cc0 + c) * CBD + kt + kk];
      }
      __syncthreads();
#pragma unroll
      for (int kk = 0; kk < 16; ++kk){
        float tv[4];
#pragma unroll
        for (int i = 0; i < 4; ++i) tv[i] = tl[rg * 4 + i][kt + kk];
#pragma unroll
        for (int j = 0; j < 8; ++j){
          float cv = cl[kk][cg + 64 * j];
#pragma unroll
          for (int i = 0; i < 4; ++i) acc[i][j] = fmaf(tv[i], cv, acc[i][j]);
        }
      }
    }
#pragma unroll
    for (int j = 0; j < 8; ++j){
      int c = cc0 + cg + 64 * j;
      float nrm = cbn[c];
#pragma unroll
      for (int i = 0; i < 4; ++i){
        float d = nrm - 2.f * acc[i][j];
        if (d < minv[i]){ minv[i] = d; mini[i] = c; }   // strict < keeps first (ascending c)
      }
    }
  }
#pragma unroll
  for (int i = 0; i < 4; ++i){ rv[rg * 4 + i][cg] = minv[i]; ri[rg * 4 + i][cg] = mini[i]; }
  __syncthreads();
  if (tid < 16){
    float bv = rv[tid][0]; int bi = ri[tid][0];
    for (int g = 1; g < 64; ++g){
      float v = rv[tid][g]; int ii = ri[tid][g];
      if (v < bv || (v == bv && ii < bi)){ bv = v; bi = ii; }
    }
    int n = row0 + tid, b = n / T2_, t2 = n - b * T2_;
    out_lb[n] = (t2 < label_len(len[b])) ? (float)(bi + 1) : 0.f;
  }
}

// ---------------- kernel 5: mask (threefry uniform, bit-exact) ----------------
__device__ inline void emit_mask(const int* len, float* md, int i, uint32_t bits){
  float u = __uint_as_float((bits >> 9) | 0x3F800000u) - 1.0f;
  int b = i / T2_, t2 = i - b * T2_;
  bool m = (u < 0.1f) && (t2 < label_len(len[b]));
  md[i] = m ? 1.0f : 0.0f;
}

__global__ void mask_k(const int* __restrict__ len, float* __restrict__ md, uint32_t km0, uint32_t km1){
  int j = blockIdx.x * 256 + threadIdx.x;
  if (j >= HMASK) return;
  uint32_t x0 = (uint32_t)j, x1 = (uint32_t)(j + HMASK);
  tf2x32(km0, km1, x0, x1);
  emit_mask(len, md, j, x0);
  emit_mask(len, md, j + HMASK, x1);
}

// ---------------- kernel 6: masked_feats (threefry normal, bit-exact bits) ----------------
__device__ inline void emit_feat(const float* aug, const float* md, float* mf, int i, uint32_t bits){
  int tabs = i / D_;
  int t = tabs & (T_ - 1);
  int b = i / (D_ * T_);
  int lo = (t < 3) ? 0 : ((t - 3) >> 2);   // ceil((t-6)/4) clamped to 0
  int hi = t >> 2; if (hi > T2_ - 1) hi = T2_ - 1;
  bool m = false;
  for (int t2 = lo; t2 <= hi; ++t2) m = m || (md[b * T2_ + t2] != 0.f);
  float v;
  if (m){
    float f = __uint_as_float((bits >> 9) | 0x3F800000u) - 1.0f;
    const float LOV = -0.99999994f;                 // nextafter(-1,0) in f32
    float u = fmaf(f, 2.0f, LOV);                   // f*2 exact -> identical to mul+add
    u = fmaxf(LOV, u);
    v = 0.1f * (1.41421356f * erfinv_f(u));         // NOISE_STD * (sqrt2_f32 * erfinv)
  } else {
    v = aug[i];
  }
  mf[i] = v;
}

__global__ void feats_k(const float* __restrict__ aug, const float* __restrict__ md,
                        float* __restrict__ mf, uint32_t kn0, uint32_t kn1){
  int j = blockIdx.x * 256 + threadIdx.x;   // grid covers exactly HN
  uint32_t x0 = (uint32_t)j, x1 = (uint32_t)(j + HN);
  tf2x32(kn0, kn1, x0, x1);
  emit_feat(aug, md, mf, j, x0);
  emit_feat(aug, md, mf, j + HN, x1);
}

// ---------------- host ----------------
extern "C" void kernel_launch(void* const* d_in, const int* in_sizes, int n_in,
                              void* d_out, int out_size, void* d_ws, size_t ws_size,
                              hipStream_t stream){
  const float* raw  = (const float*)d_in[0];
  const float* aug  = (const float*)d_in[1];
  const int*   len  = (const int*)  d_in[2];
  const float* proj = (const float*)d_in[3];
  const float* cb   = (const float*)d_in[4];

  float* out = (float*)d_out;
  float* mf  = out;                       // (B,T,D)   5,242,880
  float* lb  = out + 5242880;             // (1,B,T2)     16,352
  float* md  = out + 5259232;             // (B,T2)       16,352

  float* W    = (float*)d_ws;
  float* cbn  = W;                        // 1024
  float* S    = W + 1024;                 // 16352*720
  float* Tm   = W + 1024 + NROW * GK;     // 16352*512

  // JAX: key(42) -> split -> (km, kn); threefry on counts [0,1,2,3]
  uint32_t a0 = 0u, a1 = 2u, b0 = 1u, b1 = 3u;
  tf2x32(0u, 42u, a0, a1);
  tf2x32(0u, 42u, b0, b1);
  uint32_t km0 = a0, km1 = b0, kn0 = a1, kn1 = b1;

  cbnorm_k<<<CBS, 64, 0, stream>>>(cb, cbn);
  gather_k<<<(NROW * GK) / 256, 256, 0, stream>>>(raw, S);
  gemm1_k<<<dim3(CBD / 64, 128), 256, 0, stream>>>(S, proj, Tm);
  dist_k<<<NROW / 16, 256, 0, stream>>>(Tm, cb, cbn, len, lb);
  mask_k<<<(HMASK + 255) / 256, 256, 0, stream>>>(len, md, km0, km1);
  feats_k<<<HN / 256, 256, 0, stream>>>(aug, md, mf, kn0, kn1);
}

// Round 2
// 450.200 us; speedup vs baseline: 3.0602x; 3.0602x over previous
//
#include <hip/hip_runtime.h>
#include <cstdint>

#define B_    32
#define T_    2048
#define D_    80
#define T2_   511
#define NROW  16352      // B_*T2_
#define GK    720        // INPUT_DIM
#define CBD   512
#define CBS   1024
#define HMASK 8176       // 16352/2
#define HN    2621440    // B_*T_*D_/2

// ---------------- threefry2x32 (exact JAX schedule) ----------------
__host__ __device__ inline uint32_t rotl_(uint32_t v, int d){ return (v<<d)|(v>>(32-d)); }

__host__ __device__ inline void tf2x32(uint32_t k0, uint32_t k1, uint32_t& x0, uint32_t& x1){
  uint32_t ks2 = k0 ^ k1 ^ 0x1BD11BDAu;
  x0 += k0; x1 += k1;
  const int r0[4] = {13,15,26,6}, r1[4] = {17,29,16,24};
#pragma unroll
  for (int i=0;i<4;i++){ x0 += x1; x1 = rotl_(x1, r0[i]); x1 ^= x0; }
  x0 += k1; x1 += ks2 + 1u;
#pragma unroll
  for (int i=0;i<4;i++){ x0 += x1; x1 = rotl_(x1, r1[i]); x1 ^= x0; }
  x0 += ks2; x1 += k0 + 2u;
#pragma unroll
  for (int i=0;i<4;i++){ x0 += x1; x1 = rotl_(x1, r0[i]); x1 ^= x0; }
  x0 += k0; x1 += k1 + 3u;
#pragma unroll
  for (int i=0;i<4;i++){ x0 += x1; x1 = rotl_(x1, r1[i]); x1 ^= x0; }
  x0 += k1; x1 += ks2 + 4u;
#pragma unroll
  for (int i=0;i<4;i++){ x0 += x1; x1 = rotl_(x1, r0[i]); x1 ^= x0; }
  x0 += ks2; x1 += k0 + 5u;
}

// XLA ErfInv32 (Giles) — matches lax.erf_inv f32
__device__ inline float erfinv_f(float x){
  float w = -log1pf(-x*x);
  float p;
  if (w < 5.0f){
    w -= 2.5f;
    p = 2.81022636e-08f;
    p = fmaf(p, w, 3.43273939e-07f);
    p = fmaf(p, w, -3.5233877e-06f);
    p = fmaf(p, w, -4.39150654e-06f);
    p = fmaf(p, w, 0.00021858087f);
    p = fmaf(p, w, -0.00125372503f);
    p = fmaf(p, w, -0.00417768164f);
    p = fmaf(p, w, 0.246640727f);
    p = fmaf(p, w, 1.50140941f);
  } else {
    w = sqrtf(w) - 3.0f;
    p = -0.000200214257f;
    p = fmaf(p, w, 0.000100950558f);
    p = fmaf(p, w, 0.00134934322f);
    p = fmaf(p, w, -0.00367342844f);
    p = fmaf(p, w, 0.00573950773f);
    p = fmaf(p, w, -0.0076224613f);
    p = fmaf(p, w, 0.00943887047f);
    p = fmaf(p, w, 1.00167406f);
    p = fmaf(p, w, 2.83297682f);
  }
  return p * x;
}

__device__ inline int label_len(int L){ return (((L - 3) / 2) - 2) / 2 + 1; }

// ---------------- kernel 1: codebook norms (fp64 acc) ----------------
__global__ void cbnorm_k(const float* __restrict__ cb, float* __restrict__ cbn){
  int c = blockIdx.x, lane = threadIdx.x;
  double s = 0.0;
  for (int k = lane; k < CBD; k += 64){ float v = cb[c*CBD + k]; s += (double)v * (double)v; }
#pragma unroll
  for (int off = 32; off; off >>= 1) s += __shfl_down(s, off);
  if (lane == 0) cbn[c] = (float)s;
}

// ---------------- kernel 2: gather stacked S (coalesced write) ----------------
__global__ void gather_k(const float* __restrict__ raw, float* __restrict__ S){
  int idx = blockIdx.x * 256 + threadIdx.x;   // grid sized exactly NROW*GK
  int n = idx / GK, k = idx - n * GK;
  int b = n / T2_, t2 = n - b * T2_;
  int d = k / 9, rem = k - d * 9;
  int k1 = rem / 3, k2 = rem - 3 * k1;
  int tm = 4 * t2 + 2 * k2 + k1;
  S[idx] = raw[(b * T_ + tm) * D_ + d];
}

// ---------------- kernel 3: W = P(720x512) * cb^T(512x1024) ----------------
__global__ __launch_bounds__(256) void wgemm_k(const float* __restrict__ P, const float* __restrict__ cb,
                                               float* __restrict__ W){
  __shared__ float sP[16][68];   // [kk][r], 64 rows
  __shared__ float sC[16][68];   // [kk][c], 64 cols
  int r0 = blockIdx.y * 64, c0 = blockIdx.x * 64;
  int tid = threadIdx.x, tx = tid & 15, ty = tid >> 4;
  float acc[4][4] = {};
  for (int k0 = 0; k0 < CBD; k0 += 16){
    __syncthreads();
    {
      int r = tid >> 2, kq = tid & 3;
      int rr = r0 + r;
      float4 v = {0.f,0.f,0.f,0.f};
      if (rr < GK) v = *(const float4*)&P[rr * CBD + k0 + kq * 4];
      sP[kq*4+0][r] = v.x; sP[kq*4+1][r] = v.y; sP[kq*4+2][r] = v.z; sP[kq*4+3][r] = v.w;
      float4 w = *(const float4*)&cb[(c0 + r) * CBD + k0 + kq * 4];
      sC[kq*4+0][r] = w.x; sC[kq*4+1][r] = w.y; sC[kq*4+2][r] = w.z; sC[kq*4+3][r] = w.w;
    }
    __syncthreads();
#pragma unroll
    for (int kk = 0; kk < 16; ++kk){
      float4 a = *(const float4*)&sP[kk][ty * 4];
      float4 b = *(const float4*)&sC[kk][tx * 4];
      float av[4] = {a.x,a.y,a.z,a.w}, bv[4] = {b.x,b.y,b.z,b.w};
#pragma unroll
      for (int i = 0; i < 4; ++i)
#pragma unroll
        for (int j = 0; j < 4; ++j) acc[i][j] = fmaf(av[i], bv[j], acc[i][j]);
    }
  }
#pragma unroll
  for (int i = 0; i < 4; ++i){
    int r = r0 + ty * 4 + i;
    if (r < GK){
      float4 o; o.x = acc[i][0]; o.y = acc[i][1]; o.z = acc[i][2]; o.w = acc[i][3];
      *(float4*)&W[r * CBS + c0 + tx * 4] = o;
    }
  }
}

// ---------------- kernel 4: score = S*W, fused argmin over 128-col block ----------------
__global__ __launch_bounds__(256) void score_k(const float* __restrict__ S, const float* __restrict__ W,
                                               const float* __restrict__ cbn,
                                               float* __restrict__ pval, int* __restrict__ pidx){
  __shared__ float sA[16][132];   // [kk][row]
  __shared__ float sB[16][132];   // [kk][col]
  int n0 = blockIdx.y * 128, c0 = blockIdx.x * 128;
  int tid = threadIdx.x, tx = tid & 15, ty = tid >> 4;
  float acc[8][8] = {};
  for (int k0 = 0; k0 < GK; k0 += 16){
    __syncthreads();
#pragma unroll
    for (int i = 0; i < 2; ++i){
      int q = tid + i * 256;
      int r = q >> 2, kq = q & 3;
      int n = n0 + r;
      float4 v = {0.f,0.f,0.f,0.f};
      if (n < NROW) v = *(const float4*)&S[n * GK + k0 + kq * 4];
      sA[kq*4+0][r] = v.x; sA[kq*4+1][r] = v.y; sA[kq*4+2][r] = v.z; sA[kq*4+3][r] = v.w;
    }
#pragma unroll
    for (int i = 0; i < 2; ++i){
      int q = tid + i * 256;
      int c4 = q & 31, kk = q >> 5;
      float4 v = *(const float4*)&W[(k0 + kk) * CBS + c0 + c4 * 4];
      *(float4*)&sB[kk][c4 * 4] = v;
    }
    __syncthreads();
#pragma unroll
    for (int kk = 0; kk < 16; ++kk){
      float4 a0 = *(const float4*)&sA[kk][ty * 4];
      float4 a1 = *(const float4*)&sA[kk][64 + ty * 4];
      float4 b0 = *(const float4*)&sB[kk][tx * 4];
      float4 b1 = *(const float4*)&sB[kk][64 + tx * 4];
      float av[8] = {a0.x,a0.y,a0.z,a0.w,a1.x,a1.y,a1.z,a1.w};
      float bv[8] = {b0.x,b0.y,b0.z,b0.w,b1.x,b1.y,b1.z,b1.w};
#pragma unroll
      for (int i = 0; i < 8; ++i)
#pragma unroll
        for (int j = 0; j < 8; ++j) acc[i][j] = fmaf(av[i], bv[j], acc[i][j]);
    }
  }
  // epilogue: d = cbn[c] - 2*score ; per-thread argmin (cols ascending), then LDS reduce across tx
  float cn[8];
#pragma unroll
  for (int j = 0; j < 8; ++j){
    int c = c0 + ((j < 4) ? (tx * 4 + j) : (64 + tx * 4 + j - 4));
    cn[j] = cbn[c];
  }
  float mval[8]; int midx[8];
#pragma unroll
  for (int i = 0; i < 8; ++i){
    float bv = 1e30f; int bi = 0;
#pragma unroll
    for (int j = 0; j < 8; ++j){   // j ascending == col ascending within this thread
      int c = c0 + ((j < 4) ? (tx * 4 + j) : (64 + tx * 4 + j - 4));
      float d = fmaf(-2.f, acc[i][j], cn[j]);
      if (d < bv){ bv = d; bi = c; }
    }
    mval[i] = bv; midx[i] = bi;
  }
  __syncthreads();
  float* rv = &sA[0][0];                 // 128 rows x 16 tx floats (2048 <= 2112)
  int*   ri = (int*)&sB[0][0];
#pragma unroll
  for (int i = 0; i < 8; ++i){
    int r = (i < 4) ? (ty * 4 + i) : (64 + ty * 4 + i - 4);
    rv[r * 16 + tx] = mval[i];
    ri[r * 16 + tx] = midx[i];
  }
  __syncthreads();
  if (tid < 128){
    float bv = rv[tid * 16]; int bi = ri[tid * 16];
#pragma unroll
    for (int g = 1; g < 16; ++g){
      float v = rv[tid * 16 + g]; int ii = ri[tid * 16 + g];
      if (v < bv || (v == bv && ii < bi)){ bv = v; bi = ii; }
    }
    int n = n0 + tid;
    if (n < NROW){
      pval[blockIdx.x * NROW + n] = bv;
      pidx[blockIdx.x * NROW + n] = bi;
    }
  }
}

// ---------------- kernel 5: combine partial argmins -> labels ----------------
__global__ void combine_k(const float* __restrict__ pval, const int* __restrict__ pidx,
                          const int* __restrict__ len, float* __restrict__ lb){
  int n = blockIdx.x * 256 + threadIdx.x;
  if (n >= NROW) return;
  float bv = pval[n]; int bi = pidx[n];
#pragma unroll
  for (int bx = 1; bx < 8; ++bx){
    float v = pval[bx * NROW + n]; int ii = pidx[bx * NROW + n];
    if (v < bv || (v == bv && ii < bi)){ bv = v; bi = ii; }
  }
  int b = n / T2_, t2 = n - b * T2_;
  lb[n] = (t2 < label_len(len[b])) ? (float)(bi + 1) : 0.f;
}

// ---------------- kernel 6: mask (threefry uniform, bit-exact) ----------------
__device__ inline void emit_mask(const int* len, float* md, int i, uint32_t bits){
  float u = __uint_as_float((bits >> 9) | 0x3F800000u) - 1.0f;
  int b = i / T2_, t2 = i - b * T2_;
  bool m = (u < 0.1f) && (t2 < label_len(len[b]));
  md[i] = m ? 1.0f : 0.0f;
}

__global__ void mask_k(const int* __restrict__ len, float* __restrict__ md, uint32_t km0, uint32_t km1){
  int j = blockIdx.x * 256 + threadIdx.x;
  if (j >= HMASK) return;
  uint32_t x0 = (uint32_t)j, x1 = (uint32_t)(j + HMASK);
  tf2x32(km0, km1, x0, x1);
  emit_mask(len, md, j, x0);
  emit_mask(len, md, j + HMASK, x1);
}

// ---------------- kernel 7: masked_feats (threefry normal, bit-exact bits) ----------------
__device__ inline void emit_feat(const float* aug, const float* md, float* mf, int i, uint32_t bits){
  int tabs = i / D_;
  int t = tabs & (T_ - 1);
  int b = i / (D_ * T_);
  int lo = (t < 3) ? 0 : ((t - 3) >> 2);
  int hi = t >> 2; if (hi > T2_ - 1) hi = T2_ - 1;
  bool m = false;
  for (int t2 = lo; t2 <= hi; ++t2) m = m || (md[b * T2_ + t2] != 0.f);
  float v;
  if (m){
    float f = __uint_as_float((bits >> 9) | 0x3F800000u) - 1.0f;
    const float LOV = -0.99999994f;
    float u = fmaf(f, 2.0f, LOV);
    u = fmaxf(LOV, u);
    v = 0.1f * (1.41421356f * erfinv_f(u));
  } else {
    v = aug[i];
  }
  mf[i] = v;
}

__global__ void feats_k(const float* __restrict__ aug, const float* __restrict__ md,
                        float* __restrict__ mf, uint32_t kn0, uint32_t kn1){
  int j = blockIdx.x * 256 + threadIdx.x;
  uint32_t x0 = (uint32_t)j, x1 = (uint32_t)(j + HN);
  tf2x32(kn0, kn1, x0, x1);
  emit_feat(aug, md, mf, j, x0);
  emit_feat(aug, md, mf, j + HN, x1);
}

// ---------------- host ----------------
extern "C" void kernel_launch(void* const* d_in, const int* in_sizes, int n_in,
                              void* d_out, int out_size, void* d_ws, size_t ws_size,
                              hipStream_t stream){
  const float* raw  = (const float*)d_in[0];
  const float* aug  = (const float*)d_in[1];
  const int*   len  = (const int*)  d_in[2];
  const float* proj = (const float*)d_in[3];
  const float* cb   = (const float*)d_in[4];

  float* out = (float*)d_out;
  float* mf  = out;                       // (B,T,D)   5,242,880
  float* lb  = out + 5242880;             // (1,B,T2)     16,352
  float* md  = out + 5259232;             // (B,T2)       16,352

  float* Wks  = (float*)d_ws;
  float* cbn  = Wks;                                   // 1024
  float* Wm   = Wks + 1024;                            // 720*1024   = 737,280
  float* S    = Wm + GK * CBS;                         // 16352*720  = 11,773,440
  float* pval = S + (size_t)NROW * GK;                 // 8*16352    = 130,816
  int*   pidx = (int*)(pval + 8 * NROW);               // 8*16352

  // JAX: key(42) -> split -> (km, kn); threefry on counts [0,1,2,3]
  uint32_t a0 = 0u, a1 = 2u, b0 = 1u, b1 = 3u;
  tf2x32(0u, 42u, a0, a1);
  tf2x32(0u, 42u, b0, b1);
  uint32_t km0 = a0, km1 = b0, kn0 = a1, kn1 = b1;

  cbnorm_k<<<CBS, 64, 0, stream>>>(cb, cbn);
  wgemm_k<<<dim3(CBS / 64, (GK + 63) / 64), 256, 0, stream>>>(proj, cb, Wm);
  gather_k<<<(NROW * GK) / 256, 256, 0, stream>>>(raw, S);
  score_k<<<dim3(CBS / 128, (NROW + 127) / 128), 256, 0, stream>>>(S, Wm, cbn, pval, pidx);
  combine_k<<<(NROW + 255) / 256, 256, 0, stream>>>(pval, pidx, len, lb);
  mask_k<<<(HMASK + 255) / 256, 256, 0, stream>>>(len, md, km0, km1);
  feats_k<<<HN / 256, 256, 0, stream>>>(aug, md, mf, kn0, kn1);
}

// Round 3
// 179.459 us; speedup vs baseline: 7.6770x; 2.5087x over previous
//
#include <hip/hip_runtime.h>
#include <cstdint>

#define B_    32
#define T_    2048
#define D_    80
#define T2_   511
#define NROW  16352      // B_*T2_
#define GK    720        // INPUT_DIM
#define CBD   512
#define CBS   1024
#define HMASK 8176       // 16352/2
#define HN    2621440    // B_*T_*D_/2
#define NP    16384      // padded rows
#define KB    23         // 736/32 k-blocks (k=720 is the norm-augment slot)

using bfrag = __attribute__((ext_vector_type(8))) short;   // 8 bf16 = 4 VGPR
using f32x4 = __attribute__((ext_vector_type(4))) float;
using s4    = __attribute__((ext_vector_type(4))) short;

__device__ inline ushort f2bf(float f){                    // RNE f32->bf16
  uint32_t u = __float_as_uint(f);
  uint32_t r = (u + 0x7FFFu + ((u >> 16) & 1u)) >> 16;
  return (ushort)r;
}
__device__ inline float bf2f(ushort h){ return __uint_as_float(((uint32_t)h) << 16); }

#define GLL16(gsrc, ldst) __builtin_amdgcn_global_load_lds( \
    (__attribute__((address_space(1))) void*)(gsrc), \
    (__attribute__((address_space(3))) void*)(ldst), 16, 0, 0)

// ---------------- threefry2x32 (exact JAX schedule) ----------------
__host__ __device__ inline uint32_t rotl_(uint32_t v, int d){ return (v<<d)|(v>>(32-d)); }

__host__ __device__ inline void tf2x32(uint32_t k0, uint32_t k1, uint32_t& x0, uint32_t& x1){
  uint32_t ks2 = k0 ^ k1 ^ 0x1BD11BDAu;
  x0 += k0; x1 += k1;
  const int r0[4] = {13,15,26,6}, r1[4] = {17,29,16,24};
#pragma unroll
  for (int i=0;i<4;i++){ x0 += x1; x1 = rotl_(x1, r0[i]); x1 ^= x0; }
  x0 += k1; x1 += ks2 + 1u;
#pragma unroll
  for (int i=0;i<4;i++){ x0 += x1; x1 = rotl_(x1, r1[i]); x1 ^= x0; }
  x0 += ks2; x1 += k0 + 2u;
#pragma unroll
  for (int i=0;i<4;i++){ x0 += x1; x1 = rotl_(x1, r0[i]); x1 ^= x0; }
  x0 += k0; x1 += k1 + 3u;
#pragma unroll
  for (int i=0;i<4;i++){ x0 += x1; x1 = rotl_(x1, r1[i]); x1 ^= x0; }
  x0 += k1; x1 += ks2 + 4u;
#pragma unroll
  for (int i=0;i<4;i++){ x0 += x1; x1 = rotl_(x1, r0[i]); x1 ^= x0; }
  x0 += ks2; x1 += k0 + 5u;
}

// XLA ErfInv32 (Giles) — matches lax.erf_inv f32
__device__ inline float erfinv_f(float x){
  float w = -log1pf(-x*x);
  float p;
  if (w < 5.0f){
    w -= 2.5f;
    p = 2.81022636e-08f;
    p = fmaf(p, w, 3.43273939e-07f);
    p = fmaf(p, w, -3.5233877e-06f);
    p = fmaf(p, w, -4.39150654e-06f);
    p = fmaf(p, w, 0.00021858087f);
    p = fmaf(p, w, -0.00125372503f);
    p = fmaf(p, w, -0.00417768164f);
    p = fmaf(p, w, 0.246640727f);
    p = fmaf(p, w, 1.50140941f);
  } else {
    w = sqrtf(w) - 3.0f;
    p = -0.000200214257f;
    p = fmaf(p, w, 0.000100950558f);
    p = fmaf(p, w, 0.00134934322f);
    p = fmaf(p, w, -0.00367342844f);
    p = fmaf(p, w, 0.00573950773f);
    p = fmaf(p, w, -0.0076224613f);
    p = fmaf(p, w, 0.00943887047f);
    p = fmaf(p, w, 1.00167406f);
    p = fmaf(p, w, 2.83297682f);
  }
  return p * x;
}

__device__ inline int label_len(int L){ return (((L - 3) / 2) - 2) / 2 + 1; }

// ---------------- kernel 1: codebook norms -> augment row (k=720) of W panels ----------------
__global__ void cbnorm_k(const float* __restrict__ cb, ushort* __restrict__ W0, ushort* __restrict__ W1){
  int c = blockIdx.x, lane = threadIdx.x;
  double s = 0.0;
  for (int k = lane; k < CBD; k += 64){ float v = cb[c*CBD + k]; s += (double)v * (double)v; }
#pragma unroll
  for (int off = 32; off; off >>= 1) s += __shfl_down(s, off);
  float nf = (float)s;
  nf = __shfl(nf, 0);
  size_t base = ((size_t)(KB-1)*CBS + c)*32;
  if (lane == 16){
    float h = -0.5f * nf;
    ushort h0 = f2bf(h); ushort h1 = f2bf(h - bf2f(h0));
    W0[base+16] = h0; W1[base+16] = h1;
  } else if (lane > 16 && lane < 32){
    W0[base+lane] = 0; W1[base+lane] = 0;
  }
}

// ---------------- kernel 2: gather stacked S -> split bf16 k-panels [kb][n][kk] ----------------
__global__ void gather_k(const float* __restrict__ raw, ushort* __restrict__ S0, ushort* __restrict__ S1){
  int idx4 = blockIdx.x * 256 + threadIdx.x;    // one thread = 4 consecutive kk
  int kk4 = idx4 & 7;
  int n   = (idx4 >> 3) & (NP - 1);
  int kb  = idx4 >> 17;                          // NP*8 = 2^17
  int b = n / T2_, t2 = n - b * T2_;
  s4 o0, o1;
#pragma unroll
  for (int j = 0; j < 4; ++j){
    int k = kb*32 + kk4*4 + j;
    float v = 0.f;
    if (n < NROW){
      if (k < GK){
        int d = k / 9, rem = k - 9*d;
        int k1 = rem / 3, k2 = rem - 3*k1;
        int tm = 4*t2 + 2*k2 + k1;
        v = raw[(b * T_ + tm) * D_ + d];
      } else if (k == GK) v = 1.f;               // norm-augment slot
    }
    ushort h0 = f2bf(v); ushort h1 = f2bf(v - bf2f(h0));
    o0[j] = (short)h0; o1[j] = (short)h1;
  }
  size_t off = ((size_t)kb*NP + n)*32 + kk4*4;
  *(s4*)&S0[off] = o0;
  *(s4*)&S1[off] = o1;
}

// ---------------- kernel 3: W = P(720x512)*cb^T -> split bf16 k-panels [kb][c][kk] ----------------
__global__ __launch_bounds__(256) void wgemm_k(const float* __restrict__ P, const float* __restrict__ cb,
                                               ushort* __restrict__ W0, ushort* __restrict__ W1){
  __shared__ float sP[16][68];
  __shared__ float sC[16][68];
  int r0 = blockIdx.y * 64, c0 = blockIdx.x * 64;
  int tid = threadIdx.x, tx = tid & 15, ty = tid >> 4;
  float acc[4][4] = {};
  for (int k0 = 0; k0 < CBD; k0 += 16){
    __syncthreads();
    {
      int r = tid >> 2, kq = tid & 3;
      int rr = r0 + r;
      float4 v = {0.f,0.f,0.f,0.f};
      if (rr < GK) v = *(const float4*)&P[rr * CBD + k0 + kq * 4];
      sP[kq*4+0][r] = v.x; sP[kq*4+1][r] = v.y; sP[kq*4+2][r] = v.z; sP[kq*4+3][r] = v.w;
      float4 w = *(const float4*)&cb[(c0 + r) * CBD + k0 + kq * 4];
      sC[kq*4+0][r] = w.x; sC[kq*4+1][r] = w.y; sC[kq*4+2][r] = w.z; sC[kq*4+3][r] = w.w;
    }
    __syncthreads();
#pragma unroll
    for (int kk = 0; kk < 16; ++kk){
      float4 a = *(const float4*)&sP[kk][ty * 4];
      float4 b = *(const float4*)&sC[kk][tx * 4];
      float av[4] = {a.x,a.y,a.z,a.w}, bv[4] = {b.x,b.y,b.z,b.w};
#pragma unroll
      for (int i = 0; i < 4; ++i)
#pragma unroll
        for (int j = 0; j < 4; ++j) acc[i][j] = fmaf(av[i], bv[j], acc[i][j]);
    }
  }
#pragma unroll
  for (int i = 0; i < 4; ++i){
    int r = r0 + ty * 4 + i;
    if (r < GK){
#pragma unroll
      for (int j = 0; j < 4; ++j){
        int c = c0 + tx * 4 + j;
        float v = acc[i][j];
        ushort h0 = f2bf(v); ushort h1 = f2bf(v - bf2f(h0));
        size_t o = ((size_t)(r >> 5) * CBS + c) * 32 + (r & 31);
        W0[o] = h0; W1[o] = h1;
      }
    }
  }
}

// ---------------- kernel 4: score = S*W via 3-pass bf16 MFMA, fused argmin ----------------
__global__ __launch_bounds__(256) void score_k(const ushort* __restrict__ S0, const ushort* __restrict__ S1,
                                               const ushort* __restrict__ W0, const ushort* __restrict__ W1,
                                               float* __restrict__ pval, int* __restrict__ pidx){
  __shared__ __align__(16) ushort lA[2][128*32];
  __shared__ __align__(16) ushort lB[2][128*32];
  int tid = threadIdx.x;
  int lane = tid & 63, wid = tid >> 6;
  int wm = wid >> 1, wn = wid & 1;        // 2x2 waves -> 64x64 tiles
  int g = lane >> 4, lr = lane & 15;
  int n0 = blockIdx.y * 128, c0 = blockIdx.x * 128;
  f32x4 acc[4][4] = {};
  for (int kb = 0; kb < KB; ++kb){
    const ushort* src; ushort* dst;
    if      (wid == 0){ src = S0 + ((size_t)kb*NP  + n0)*32; dst = &lA[0][0]; }
    else if (wid == 1){ src = S1 + ((size_t)kb*NP  + n0)*32; dst = &lA[1][0]; }
    else if (wid == 2){ src = W0 + ((size_t)kb*CBS + c0)*32; dst = &lB[0][0]; }
    else              { src = W1 + ((size_t)kb*CBS + c0)*32; dst = &lB[1][0]; }
    __syncthreads();
#pragma unroll
    for (int q = 0; q < 8; ++q)
      GLL16(src + q*512 + lane*8, dst + q*512);
    __syncthreads();
    bfrag a[2][4], bfr[2][4];
#pragma unroll
    for (int mt = 0; mt < 4; ++mt){
      int m = wm*64 + mt*16 + lr;
      a[0][mt] = *(const bfrag*)&lA[0][m*32 + g*8];
      a[1][mt] = *(const bfrag*)&lA[1][m*32 + g*8];
    }
#pragma unroll
    for (int nt = 0; nt < 4; ++nt){
      int c = wn*64 + nt*16 + lr;
      bfr[0][nt] = *(const bfrag*)&lB[0][c*32 + g*8];
      bfr[1][nt] = *(const bfrag*)&lB[1][c*32 + g*8];
    }
#pragma unroll
    for (int mt = 0; mt < 4; ++mt)
#pragma unroll
      for (int nt = 0; nt < 4; ++nt){
        acc[mt][nt] = __builtin_amdgcn_mfma_f32_16x16x32_bf16(a[0][mt], bfr[0][nt], acc[mt][nt], 0,0,0);
        acc[mt][nt] = __builtin_amdgcn_mfma_f32_16x16x32_bf16(a[0][mt], bfr[1][nt], acc[mt][nt], 0,0,0);
        acc[mt][nt] = __builtin_amdgcn_mfma_f32_16x16x32_bf16(a[1][mt], bfr[0][nt], acc[mt][nt], 0,0,0);
      }
  }
  // epilogue: dist = -2*acc (norms folded in); per-row argmin, first-index tie-break
  float bv[4][4]; int bi[4][4];
#pragma unroll
  for (int mt = 0; mt < 4; ++mt)
#pragma unroll
    for (int r = 0; r < 4; ++r){
      float best = 3.4e38f; int besti = 0;
#pragma unroll
      for (int nt = 0; nt < 4; ++nt){      // nt ascending == col ascending
        float d = -2.f * acc[mt][nt][r];
        int c = c0 + wn*64 + nt*16 + lr;
        if (d < best){ best = d; besti = c; }
      }
      bv[mt][r] = best; bi[mt][r] = besti;
    }
#pragma unroll
  for (int off = 1; off < 16; off <<= 1){
#pragma unroll
    for (int mt = 0; mt < 4; ++mt)
#pragma unroll
      for (int r = 0; r < 4; ++r){
        float ov = __shfl_xor(bv[mt][r], off);
        int   oi = __shfl_xor(bi[mt][r], off);
        if (ov < bv[mt][r] || (ov == bv[mt][r] && oi < bi[mt][r])){ bv[mt][r] = ov; bi[mt][r] = oi; }
      }
  }
  if (lr == 0){
    int p = blockIdx.x*2 + wn;
#pragma unroll
    for (int mt = 0; mt < 4; ++mt)
#pragma unroll
      for (int r = 0; r < 4; ++r){
        int n = n0 + wm*64 + mt*16 + g*4 + r;
        pval[(size_t)p*NP + n] = bv[mt][r];
        pidx[(size_t)p*NP + n] = bi[mt][r];
      }
  }
}

// ---------------- kernel 5: combine 16 partial argmins -> labels ----------------
__global__ void combine_k(const float* __restrict__ pval, const int* __restrict__ pidx,
                          const int* __restrict__ len, float* __restrict__ lb){
  int n = blockIdx.x * 256 + threadIdx.x;
  if (n >= NROW) return;
  float bv = pval[n]; int bi = pidx[n];
#pragma unroll
  for (int p = 1; p < 16; ++p){
    float v = pval[(size_t)p*NP + n]; int ii = pidx[(size_t)p*NP + n];
    if (v < bv || (v == bv && ii < bi)){ bv = v; bi = ii; }
  }
  int b = n / T2_, t2 = n - b * T2_;
  lb[n] = (t2 < label_len(len[b])) ? (float)(bi + 1) : 0.f;
}

// ---------------- kernel 6: mask (threefry uniform, bit-exact) ----------------
__device__ inline void emit_mask(const int* len, float* md, int i, uint32_t bits){
  float u = __uint_as_float((bits >> 9) | 0x3F800000u) - 1.0f;
  int b = i / T2_, t2 = i - b * T2_;
  bool m = (u < 0.1f) && (t2 < label_len(len[b]));
  md[i] = m ? 1.0f : 0.0f;
}

__global__ void mask_k(const int* __restrict__ len, float* __restrict__ md, uint32_t km0, uint32_t km1){
  int j = blockIdx.x * 256 + threadIdx.x;
  if (j >= HMASK) return;
  uint32_t x0 = (uint32_t)j, x1 = (uint32_t)(j + HMASK);
  tf2x32(km0, km1, x0, x1);
  emit_mask(len, md, j, x0);
  emit_mask(len, md, j + HMASK, x1);
}

// ---------------- kernel 7: masked_feats (threefry normal, bit-exact bits) ----------------
__device__ inline void emit_feat(const float* aug, const float* md, float* mf, int i, uint32_t bits){
  int tabs = i / D_;
  int t = tabs & (T_ - 1);
  int b = i / (D_ * T_);
  int lo = (t < 3) ? 0 : ((t - 3) >> 2);
  int hi = t >> 2; if (hi > T2_ - 1) hi = T2_ - 1;
  bool m = false;
  for (int t2 = lo; t2 <= hi; ++t2) m = m || (md[b * T2_ + t2] != 0.f);
  float v;
  if (m){
    float f = __uint_as_float((bits >> 9) | 0x3F800000u) - 1.0f;
    const float LOV = -0.99999994f;
    float u = fmaf(f, 2.0f, LOV);
    u = fmaxf(LOV, u);
    v = 0.1f * (1.41421356f * erfinv_f(u));
  } else {
    v = aug[i];
  }
  mf[i] = v;
}

__global__ void feats_k(const float* __restrict__ aug, const float* __restrict__ md,
                        float* __restrict__ mf, uint32_t kn0, uint32_t kn1){
  int j = blockIdx.x * 256 + threadIdx.x;
  uint32_t x0 = (uint32_t)j, x1 = (uint32_t)(j + HN);
  tf2x32(kn0, kn1, x0, x1);
  emit_feat(aug, md, mf, j, x0);
  emit_feat(aug, md, mf, j + HN, x1);
}

// ---------------- host ----------------
extern "C" void kernel_launch(void* const* d_in, const int* in_sizes, int n_in,
                              void* d_out, int out_size, void* d_ws, size_t ws_size,
                              hipStream_t stream){
  const float* raw  = (const float*)d_in[0];
  const float* aug  = (const float*)d_in[1];
  const int*   len  = (const int*)  d_in[2];
  const float* proj = (const float*)d_in[3];
  const float* cb   = (const float*)d_in[4];

  float* out = (float*)d_out;
  float* mf  = out;                       // (B,T,D)   5,242,880
  float* lb  = out + 5242880;             // (1,B,T2)     16,352
  float* md  = out + 5259232;             // (B,T2)       16,352

  ushort* w  = (ushort*)d_ws;
  ushort* W0 = w;                                   // KB*CBS*32 = 753,664 ushorts
  ushort* W1 = W0 + (size_t)KB*CBS*32;
  ushort* S0 = W1 + (size_t)KB*CBS*32;              // KB*NP*32 = 12,058,624 ushorts
  ushort* S1 = S0 + (size_t)KB*NP*32;
  float* pval = (float*)(S1 + (size_t)KB*NP*32);    // 16*NP floats
  int*   pidx = (int*)(pval + (size_t)16*NP);       // 16*NP ints

  // JAX: key(42) -> split -> (km, kn)
  uint32_t a0 = 0u, a1 = 2u, b0 = 1u, b1 = 3u;
  tf2x32(0u, 42u, a0, a1);
  tf2x32(0u, 42u, b0, b1);
  uint32_t km0 = a0, km1 = b0, kn0 = a1, kn1 = b1;

  cbnorm_k<<<CBS, 64, 0, stream>>>(cb, W0, W1);
  wgemm_k<<<dim3(CBS / 64, 12), 256, 0, stream>>>(proj, cb, W0, W1);
  gather_k<<<(KB * NP * 8) / 256, 256, 0, stream>>>(raw, S0, S1);
  score_k<<<dim3(CBS / 128, NP / 128), 256, 0, stream>>>(S0, S1, W0, W1, pval, pidx);
  combine_k<<<(NROW + 255) / 256, 256, 0, stream>>>(pval, pidx, len, lb);
  mask_k<<<(HMASK + 255) / 256, 256, 0, stream>>>(len, md, km0, km1);
  feats_k<<<HN / 256, 256, 0, stream>>>(aug, md, mf, kn0, kn1);
}